// Round 1
// 274.306 us; speedup vs baseline: 1.0544x; 1.0544x over previous
//
#include <hip/hip_runtime.h>
#include <hip/hip_bf16.h>

// Problem constants: B=32, S=512, D=256, H=8, DH=32
#define SCALE_QK 0.17677669529663687f  // 1/sqrt(32)

typedef __attribute__((ext_vector_type(8))) short short8;  // 8 bf16 (4 VGPRs)
typedef __attribute__((ext_vector_type(4))) float f32x4;

__device__ __forceinline__ ushort f2bf(float f) {  // fp32 -> bf16 RNE
  unsigned u = __float_as_uint(f);
  return (ushort)((u + 0x7FFF + ((u >> 16) & 1)) >> 16);
}

// DPP lane-move within rows of 16 (our reduction groups are exactly DPP rows).
template <int CTRL>
__device__ __forceinline__ float dpp_movf(float x) {
  return __int_as_float(
      __builtin_amdgcn_update_dpp(0, __float_as_int(x), CTRL, 0xF, 0xF, true));
}
__device__ __forceinline__ float dpp_sum16(float x) {
  x += dpp_movf<0xB1>(x);
  x += dpp_movf<0x4E>(x);
  x += dpp_movf<0x141>(x);
  x += dpp_movf<0x140>(x);
  return x;
}
__device__ __forceinline__ float dpp_max16(float x) {
  x = fmaxf(x, dpp_movf<0xB1>(x));
  x = fmaxf(x, dpp_movf<0x4E>(x));
  x = fmaxf(x, dpp_movf<0x141>(x));
  x = fmaxf(x, dpp_movf<0x140>(x));
  return x;
}

// Merged prep: blocks [0,4224): convert x/Wq/Wk to bf16 (one float4/thread).
// Blocks [4224,4480): Wvo[e][m] = sum_d Wo[e][d]*Wv[d][m] (bf16), bvo = Wo.bv+bo.
__global__ __launch_bounds__(256) void prep(
    const float *__restrict__ x, const float *__restrict__ w0,
    const float *__restrict__ w1, const float *__restrict__ Wo,
    const float *__restrict__ Wv, const float *__restrict__ bv,
    const float *__restrict__ bo, ushort *__restrict__ xbf,
    ushort *__restrict__ wbf, ushort *__restrict__ wvo,
    float *__restrict__ bvo) {
  if (blockIdx.x < 4224) {
    const long i = (long)blockIdx.x * 256 + threadIdx.x;
    const long NX4 = 16384L * 256 / 4;  // 1048576
    const float *src;
    ushort4 *dst;
    long k;
    if (i < NX4) {
      src = x; k = i; dst = (ushort4 *)xbf;
    } else {
      const long j = i - NX4;  // [0, 32768)
      const int which = (int)(j >> 14);
      k = j & 16383;
      src = which == 0 ? w0 : w1;
      dst = (ushort4 *)(wbf + which * 65536L);
    }
    const float4 v = ((const float4 *)src)[k];
    ushort4 o;
    o.x = f2bf(v.x); o.y = f2bf(v.y); o.z = f2bf(v.z); o.w = f2bf(v.w);
    dst[k] = o;
  } else {
    const int e = blockIdx.x - 4224, m = threadIdx.x;
    float acc = 0.f;
    for (int d = 0; d < 256; ++d) acc += Wo[e * 256 + d] * Wv[d * 256 + m];
    wvo[e * 256 + m] = f2bf(acc);
    if (m == 0) {
      float s = 0.f;
      for (int d = 0; d < 256; ++d) s += Wo[e * 256 + d] * bv[d];
      bvo[e] = s + bo[e];
    }
  }
}

// Unified NT bf16 MFMA GEMM (K=256): C[i][j] = dot(Y-row i, X-row j) (+bias).
// mode 1: combined Q|K projection. cols 0..255 -> Q (scale, biasA, Cq),
//         cols 256..511 -> K (no scale, biasB, Ck). bf16 [b,h,s,e] layout.
// mode 2: C bf16 T-layout [b][i][512 t] + biasA[i]   (u^T projection)
__global__ __launch_bounds__(256) void gemm_nt(
    const ushort *__restrict__ Y, const ushort *__restrict__ X,
    const float *__restrict__ biasA, const float *__restrict__ biasB,
    ushort *__restrict__ Cq, ushort *__restrict__ Ck, int mode, long yBatch,
    long xBatch) {
  const int tid = threadIdx.x;
  const int w = tid >> 6, lane = tid & 63;
  const int quad = lane >> 4, l15 = lane & 15;
  const int iLoc = blockIdx.x * 64 + w * 16 + l15;  // this lane's output row
  const int j0 = blockIdx.y * 64;
  const int b = blockIdx.z;

  const ushort *xr[4];
#pragma unroll
  for (int nt = 0; nt < 4; ++nt)
    xr[nt] = X + (long)b * xBatch + (long)(j0 + 16 * nt + l15) * 256 + quad * 8;
  const ushort *yr = Y + (long)b * yBatch + (long)iLoc * 256 + quad * 8;

  f32x4 acc[4] = {{0.f, 0.f, 0.f, 0.f},
                  {0.f, 0.f, 0.f, 0.f},
                  {0.f, 0.f, 0.f, 0.f},
                  {0.f, 0.f, 0.f, 0.f}};
#pragma unroll
  for (int ks = 0; ks < 256; ks += 32) {
    const short8 yfr = *(const short8 *)(yr + ks);
#pragma unroll
    for (int nt = 0; nt < 4; ++nt) {
      const short8 xfr = *(const short8 *)(xr[nt] + ks);
      acc[nt] = __builtin_amdgcn_mfma_f32_16x16x32_bf16(xfr, yfr, acc[nt], 0, 0, 0);
    }
  }
  // epilogue: lane holds C[iLoc][j0 + 16*nt + 4*quad + r]
#pragma unroll
  for (int nt = 0; nt < 4; ++nt) {
    const int col0 = j0 + 16 * nt + 4 * quad;
    if (mode == 1) {
      const int cq = col0 & 255;
      const float *bp = col0 < 256 ? biasA + cq : biasB + cq;
      const float4 bs = *(const float4 *)bp;
      const float scl = col0 < 256 ? SCALE_QK : 1.0f;
      ushort *base = col0 < 256 ? Cq : Ck;
      const int bb = iLoc >> 9, s = iLoc & 511;
      const int h = cq >> 5, e = cq & 31;
      ushort4 st;
      st.x = f2bf((acc[nt][0] + bs.x) * scl);
      st.y = f2bf((acc[nt][1] + bs.y) * scl);
      st.z = f2bf((acc[nt][2] + bs.z) * scl);
      st.w = f2bf((acc[nt][3] + bs.w) * scl);
      *(ushort4 *)(base + (((long)(bb << 3) + h) * 512 + s) * 32 + e) = st;
    } else {  // mode 2
      const float bd = biasA[iLoc];
      ushort4 st;
      st.x = f2bf(acc[nt][0] + bd); st.y = f2bf(acc[nt][1] + bd);
      st.z = f2bf(acc[nt][2] + bd); st.w = f2bf(acc[nt][3] + bd);
      *(ushort4 *)(Cq + ((long)b * 256 + iLoc) * 512 + col0) = st;
    }
  }
}

// Fused scores (MFMA bf16) + diag-mask + sparsemax + head-average + out-GEMM.
// Sparsemax solve: tau >= M-1 always, so only elements > M-1 are candidates
// (expected ~3 of 512/row). One top-3 min/max scan per lane replaces the max
// pass AND gives the candidate set; the tau iteration then touches only
// (q0,q1) per lane. Any lane with >=3 candidates (q2 > M-1) -> wave-uniform
// fallback to the full 32-element scan (bitwise-identical taus either way).
// Epilogue: avg rows are already in registers -> bf16 p-tile in (reused) LDS,
// MFMA against uT from L2; eliminates the separate out-GEMM kernel and its
// 33.5 MB avg re-read + fp32->bf16 conversion.
__global__ __launch_bounds__(256) void attn_sparsemax_fused(
    const ushort *__restrict__ Q, const ushort *__restrict__ K,
    const ushort *__restrict__ U, float *__restrict__ avg,
    float *__restrict__ out) {
  __shared__ f32x4 sc[16 * 128];  // 32 KB score tile; reused as bf16 p-tile
  const int tid = threadIdx.x;
  const int w = tid >> 6, lane = tid & 63;
  const int quad = lane >> 4, l15 = lane & 15;
  const int s0 = blockIdx.x * 16;
  const int b = blockIdx.y;
  const int myrow = 4 * w + quad;
  const int sglob = s0 + myrow;

  float avgacc[8][4] = {};
#pragma unroll 1
  for (int h = 0; h < 8; ++h) {
    const ushort *qh = Q + (((b << 3) + h) * 512 + s0) * 32;
    const ushort *kh = K + ((b << 3) + h) * 512 * 32;
    const short8 bq = *(const short8 *)(qh + l15 * 32 + quad * 8);
    f32x4 acc[8];
#pragma unroll
    for (int jl = 0; jl < 8; ++jl) {
      const short8 ak =
          *(const short8 *)(kh + (w * 128 + jl * 16 + l15) * 32 + quad * 8);
      acc[jl] = __builtin_amdgcn_mfma_f32_16x16x32_bf16(
          ak, bq, (f32x4){0.f, 0.f, 0.f, 0.f}, 0, 0, 0);
    }
    __syncthreads();
#pragma unroll
    for (int jl = 0; jl < 8; ++jl) {
      const int ch = 32 * w + 4 * jl + quad;
      sc[l15 * 128 + (ch ^ (l15 & 7))] = acc[jl];
    }
    __syncthreads();
    f32x4 z[8];
#pragma unroll
    for (int c = 0; c < 8; ++c) {
      const int ch = l15 + 16 * c;
      z[c] = sc[myrow * 128 + (ch ^ (myrow & 7))];
    }
#pragma unroll
    for (int c = 0; c < 8; ++c)
#pragma unroll
      for (int r = 0; r < 4; ++r)
        if (64 * c + 4 * l15 + r == sglob) z[c][r] = -1e30f;
    // top-3 scan: q0 >= q1 >= q2 of this lane's 32 values
    float q0 = -3e38f, q1 = -3e38f, q2 = -3e38f;
#pragma unroll
    for (int c = 0; c < 8; ++c)
#pragma unroll
      for (int r = 0; r < 4; ++r) {
        const float v = z[c][r];
        const float t1 = fminf(q0, v);
        q0 = fmaxf(q0, v);
        const float t2 = fminf(q1, t1);
        q1 = fmaxf(q1, t1);
        q2 = fmaxf(q2, t2);
      }
    const float M = dpp_max16(q0);
    const float thr = M - 1.0f;
    float tau = thr;
    float cOld = -1.f;
    if (__any(q2 > thr)) {
      // slow path: some lane holds >=3 candidates — full scan (rare)
#pragma unroll 1
      for (int it = 0; it < 32; ++it) {
        float s = 0.f, c = 0.f;
#pragma unroll
        for (int cc = 0; cc < 8; ++cc)
#pragma unroll
          for (int r = 0; r < 4; ++r) {
            const bool p = z[cc][r] > tau;
            s += p ? z[cc][r] : 0.f;
            c += p ? 1.f : 0.f;
          }
        s = dpp_sum16(s);
        c = dpp_sum16(c);
        const bool stable = (c == cOld);
        if (__all(stable)) break;
        if (!stable) {
          tau = (s - 1.f) / c;
          cOld = c;
        }
      }
    } else {
      // fast path: candidates per lane are within {q0,q1}; tau >= thr is
      // monotone so elements <= thr can never enter the support.
#pragma unroll 1
      for (int it = 0; it < 32; ++it) {
        const bool p0 = q0 > tau, p1 = q1 > tau;
        float s = (p0 ? q0 : 0.f) + (p1 ? q1 : 0.f);
        float c = (p0 ? 1.f : 0.f) + (p1 ? 1.f : 0.f);
        s = dpp_sum16(s);
        c = dpp_sum16(c);
        const bool stable = (c == cOld);
        if (__all(stable)) break;
        if (!stable) {
          tau = (s - 1.f) / c;
          cOld = c;
        }
      }
    }
#pragma unroll
    for (int c = 0; c < 8; ++c)
#pragma unroll
      for (int r = 0; r < 4; ++r)
        avgacc[c][r] += fmaxf(z[c][r] - tau, 0.f);
  }
  // avg write (fp32, required output) + bf16 p-tile into reused LDS.
  __syncthreads();  // all waves done reading sc for head 7
  ushort *pl = (ushort *)sc;
  float *dst = avg + ((b * 512 + sglob) << 9) + 4 * l15;
#pragma unroll
  for (int c = 0; c < 8; ++c) {
    float4 o;
    o.x = avgacc[c][0] * 0.125f;
    o.y = avgacc[c][1] * 0.125f;
    o.z = avgacc[c][2] * 0.125f;
    o.w = avgacc[c][3] * 0.125f;
    *(float4 *)(dst + 64 * c) = o;
    ushort4 pv;
    pv.x = f2bf(o.x); pv.y = f2bf(o.y); pv.z = f2bf(o.z); pv.w = f2bf(o.w);
    // row myrow, cols 64c+4*l15..+3; XOR-swizzle bits 4..6 by row (T2)
    *(ushort4 *)((char *)pl +
                 ((myrow * 1024 + 128 * c + 8 * l15) ^ ((myrow & 7) << 4))) = pv;
  }
  __syncthreads();
  // fused out = avg . u : wave w covers e in [64w, 64w+64), all 16 s-rows.
  const ushort *ub = U + (long)b * 131072 + (long)(64 * w + l15) * 512 + quad * 8;
  f32x4 oacc[4] = {{0.f, 0.f, 0.f, 0.f},
                   {0.f, 0.f, 0.f, 0.f},
                   {0.f, 0.f, 0.f, 0.f},
                   {0.f, 0.f, 0.f, 0.f}};
#pragma unroll
  for (int ks = 0; ks < 16; ++ks) {
    const short8 pf = *(const short8 *)(
        (char *)pl + (l15 * 1024 + ((ks * 64 + quad * 16) ^ ((l15 & 7) << 4))));
#pragma unroll
    for (int nt = 0; nt < 4; ++nt) {
      const short8 uf = *(const short8 *)(ub + (long)(16 * nt) * 512 + ks * 32);
      oacc[nt] = __builtin_amdgcn_mfma_f32_16x16x32_bf16(uf, pf, oacc[nt], 0, 0, 0);
    }
  }
  float *ob = out + ((long)b * 512 + s0 + l15) * 256 + 64 * w + 4 * quad;
#pragma unroll
  for (int nt = 0; nt < 4; ++nt) {
    float4 st;
    st.x = oacc[nt][0]; st.y = oacc[nt][1];
    st.z = oacc[nt][2]; st.w = oacc[nt][3];
    *(float4 *)(ob + 16 * nt) = st;
  }
}

extern "C" void kernel_launch(void* const* d_in, const int* in_sizes, int n_in,
                              void* d_out, int out_size, void* d_ws, size_t ws_size,
                              hipStream_t stream) {
  const float *x  = (const float *)d_in[0];
  const float *Wq = (const float *)d_in[1];
  const float *bq = (const float *)d_in[2];
  const float *Wk = (const float *)d_in[3];
  const float *bk = (const float *)d_in[4];
  const float *Wv = (const float *)d_in[5];
  const float *bv = (const float *)d_in[6];
  const float *Wo = (const float *)d_in[7];
  const float *bo = (const float *)d_in[8];

  float *out = (float *)d_out;                 // [B,S,D]
  float *avg = out + 32 * 512 * 256;           // [B,S,S] fp32

  // ws (ushort units): xbf | qbf | kbf | uT | wq,wk,wvo | bvo  ~= 33.9 MB
  ushort *ws16 = (ushort *)d_ws;
  ushort *xbf = ws16;                          // [16384][256] bf16
  ushort *qbf = ws16 + 4194304;                // [B,H,S,32] bf16 (pre-scaled)
  ushort *kbf = ws16 + 8388608;                // [B,H,S,32] bf16
  ushort *uT  = ws16 + 12582912;               // [B][256 e][512 t] bf16
  ushort *wbf = ws16 + 16777216;               // Wq|Wk|Wvo bf16, 65536 each
  float  *bvo = (float *)(ws16 + 16973824);    // [256] fp32

  prep<<<dim3(4480), dim3(256), 0, stream>>>(x, Wq, Wk, Wo, Wv, bv, bo, xbf,
                                             wbf, wbf + 131072, bvo);
  // Combined Q|K projection: X rows 0..511 = Wq|Wk (contiguous in wbf).
  gemm_nt<<<dim3(256, 8, 1), dim3(256), 0, stream>>>(xbf, wbf, bq, bk, qbf,
                                                     kbf, 1, 0, 0);
  // u^T projection: i = e (Y = Wvo rows), j = t (X = xbf rows of batch b).
  gemm_nt<<<dim3(4, 8, 32), dim3(256), 0, stream>>>(
      wbf + 131072, xbf, bvo, nullptr, uT, nullptr, 2, 0, 131072);
  attn_sparsemax_fused<<<dim3(32, 32), dim3(256), 0, stream>>>(qbf, kbf, uT,
                                                               avg, out);
}

// Round 2
// 231.520 us; speedup vs baseline: 1.2492x; 1.1848x over previous
//
#include <hip/hip_runtime.h>
#include <hip/hip_bf16.h>

// Problem constants: B=32, S=512, D=256, H=8, DH=32
#define SCALE_QK 0.17677669529663687f  // 1/sqrt(32)

typedef __attribute__((ext_vector_type(8))) short short8;  // 8 bf16 (4 VGPRs)
typedef __attribute__((ext_vector_type(4))) float f32x4;

__device__ __forceinline__ ushort f2bf(float f) {  // fp32 -> bf16 RNE
  unsigned u = __float_as_uint(f);
  return (ushort)((u + 0x7FFF + ((u >> 16) & 1)) >> 16);
}

// DPP lane-move within rows of 16 (our reduction groups are exactly DPP rows).
template <int CTRL>
__device__ __forceinline__ float dpp_movf(float x) {
  return __int_as_float(
      __builtin_amdgcn_update_dpp(0, __float_as_int(x), CTRL, 0xF, 0xF, true));
}
__device__ __forceinline__ float dpp_sum16(float x) {
  x += dpp_movf<0xB1>(x);
  x += dpp_movf<0x4E>(x);
  x += dpp_movf<0x141>(x);
  x += dpp_movf<0x140>(x);
  return x;
}
__device__ __forceinline__ float dpp_max16(float x) {
  x = fmaxf(x, dpp_movf<0xB1>(x));
  x = fmaxf(x, dpp_movf<0x4E>(x));
  x = fmaxf(x, dpp_movf<0x141>(x));
  x = fmaxf(x, dpp_movf<0x140>(x));
  return x;
}

// Merged prep: blocks [0,4224): convert x/Wq/Wk to bf16 (one float4/thread).
// Blocks [4224,4480): Wvo[e][m] = sum_d Wo[e][d]*Wv[d][m] (bf16), bvo = Wo.bv+bo.
__global__ __launch_bounds__(256) void prep(
    const float *__restrict__ x, const float *__restrict__ w0,
    const float *__restrict__ w1, const float *__restrict__ Wo,
    const float *__restrict__ Wv, const float *__restrict__ bv,
    const float *__restrict__ bo, ushort *__restrict__ xbf,
    ushort *__restrict__ wbf, ushort *__restrict__ wvo,
    float *__restrict__ bvo) {
  if (blockIdx.x < 4224) {
    const long i = (long)blockIdx.x * 256 + threadIdx.x;
    const long NX4 = 16384L * 256 / 4;  // 1048576
    const float *src;
    ushort4 *dst;
    long k;
    if (i < NX4) {
      src = x; k = i; dst = (ushort4 *)xbf;
    } else {
      const long j = i - NX4;  // [0, 32768)
      const int which = (int)(j >> 14);
      k = j & 16383;
      src = which == 0 ? w0 : w1;
      dst = (ushort4 *)(wbf + which * 65536L);
    }
    const float4 v = ((const float4 *)src)[k];
    ushort4 o;
    o.x = f2bf(v.x); o.y = f2bf(v.y); o.z = f2bf(v.z); o.w = f2bf(v.w);
    dst[k] = o;
  } else {
    const int e = blockIdx.x - 4224, m = threadIdx.x;
    float acc = 0.f;
    for (int d = 0; d < 256; ++d) acc += Wo[e * 256 + d] * Wv[d * 256 + m];
    wvo[e * 256 + m] = f2bf(acc);
    if (m == 0) {
      float s = 0.f;
      for (int d = 0; d < 256; ++d) s += Wo[e * 256 + d] * bv[d];
      bvo[e] = s + bo[e];
    }
  }
}

// 128-row x (16*NJ)-col NT bf16 MFMA tile body, K=256. Each wave owns two
// 16-row Y-tiles (iA, iA+64) x NJ 16-col X-tiles: 2+NJ loads -> 2*NJ MFMA
// per k-step (vs 5 loads -> 4 MFMA in the old structure).
// MODE 1: combined Q|K projection, cols<256 -> Q (scaled), else K.
// MODE 2: uT chunked layout [b][t>>5][e][t&31] bf16, + bias per e-row.
template <int NJ, int MODE>
__device__ __forceinline__ void gemm_body(
    const ushort *__restrict__ Y, const ushort *__restrict__ X,
    const float *__restrict__ bA, const float *__restrict__ bB,
    ushort *__restrict__ C0, ushort *__restrict__ C1, int iA, int j0, int b,
    int quad, int l15) {
  const ushort *xr[NJ];
#pragma unroll
  for (int nt = 0; nt < NJ; ++nt)
    xr[nt] = X + (long)(j0 + 16 * nt + l15) * 256 + quad * 8;
  const ushort *yrA = Y + (long)iA * 256 + quad * 8;

  f32x4 acc[2][NJ] = {};
#pragma unroll 1
  for (int ks = 0; ks < 256; ks += 32) {
    const short8 ya = *(const short8 *)(yrA + ks);
    const short8 yb = *(const short8 *)(yrA + 64 * 256 + ks);
#pragma unroll
    for (int nt = 0; nt < NJ; ++nt) {
      const short8 xf = *(const short8 *)(xr[nt] + ks);
      acc[0][nt] = __builtin_amdgcn_mfma_f32_16x16x32_bf16(xf, ya, acc[0][nt], 0, 0, 0);
      acc[1][nt] = __builtin_amdgcn_mfma_f32_16x16x32_bf16(xf, yb, acc[1][nt], 0, 0, 0);
    }
  }
#pragma unroll
  for (int side = 0; side < 2; ++side) {
    const int iLoc = iA + 64 * side;
#pragma unroll
    for (int nt = 0; nt < NJ; ++nt) {
      const int col0 = j0 + 16 * nt + 4 * quad;
      const f32x4 a = acc[side][nt];
      if (MODE == 1) {
        const int cq = col0 & 255;
        const float4 bs = *(const float4 *)((col0 < 256 ? bA : bB) + cq);
        const float scl = col0 < 256 ? SCALE_QK : 1.0f;
        ushort *base = col0 < 256 ? C0 : C1;
        const int bb = iLoc >> 9, s = iLoc & 511;
        const int h = cq >> 5, e = cq & 31;
        ushort4 st;
        st.x = f2bf((a[0] + bs.x) * scl);
        st.y = f2bf((a[1] + bs.y) * scl);
        st.z = f2bf((a[2] + bs.z) * scl);
        st.w = f2bf((a[3] + bs.w) * scl);
        *(ushort4 *)(base + (((long)(bb << 3) + h) * 512 + s) * 32 + e) = st;
      } else {
        const float bd = bA[iLoc];
        ushort4 st;
        st.x = f2bf(a[0] + bd); st.y = f2bf(a[1] + bd);
        st.z = f2bf(a[2] + bd); st.w = f2bf(a[3] + bd);
        *(ushort4 *)(C0 + ((long)b * 16 + (col0 >> 5)) * 8192 + iLoc * 32 +
                     (col0 & 31)) = st;
      }
    }
  }
}

// Both projection GEMMs in one launch (1024 blocks = 4/CU, fills the machine;
// both depend only on prep and run concurrently).
// gid < 512: Q|K projection, M=16384 (tokens), N=512 (Q|K), grid (128,4).
// gid >= 512: uT projection per batch, M=256 (e), N=512 (t), grid (2,8,32).
__global__ __launch_bounds__(256) void gemm_all(
    const ushort *__restrict__ xbf, const ushort *__restrict__ wqk,
    const ushort *__restrict__ wvo, const float *__restrict__ bq,
    const float *__restrict__ bk, const float *__restrict__ bvo,
    ushort *__restrict__ qbf, ushort *__restrict__ kbf,
    ushort *__restrict__ uT) {
  const int tid = threadIdx.x;
  const int w = tid >> 6, lane = tid & 63;
  const int quad = lane >> 4, l15 = lane & 15;
  const int gid = blockIdx.x;
  if (gid < 512) {
    const int bx = gid >> 2, by = gid & 3;
    const int iA = bx * 128 + w * 16 + l15;
    gemm_body<8, 1>(xbf, wqk, bq, bk, qbf, kbf, iA, by * 128, 0, quad, l15);
  } else {
    const int id2 = gid - 512;
    const int b = id2 >> 4, bx = (id2 >> 3) & 1, by = id2 & 7;
    const int iA = bx * 128 + w * 16 + l15;
    gemm_body<4, 2>(wvo, xbf + (long)b * 131072, bvo, nullptr, uT, nullptr,
                    iA, by * 64, b, quad, l15);
  }
}

// Fused scores (MFMA bf16) + diag-mask + sparsemax + head-average + out-GEMM.
// New this round: (a) next-head Q/K fragments prefetched between LDS-gather
// and the solve, so the solve's VALU time hides their L2 latency (the
// compiler's vmcnt drain lands at the next barrier, after the solve);
// (b) s_setprio(1) around MFMA clusters (T5); (c) XCD-bijective grid so all
// 32 s-blocks of a batch live on one XCD's L2 (K/Q/uT fetched once, not 8x);
// (d) uT chunked layout -> each epilogue wave-load is one 1KB segment.
__global__ __launch_bounds__(256) void attn_sparsemax_fused(
    const ushort *__restrict__ Q, const ushort *__restrict__ K,
    const ushort *__restrict__ U, float *__restrict__ avg,
    float *__restrict__ out) {
  __shared__ f32x4 sc[16 * 128];  // 32 KB score tile; reused as bf16 p-tile
  const int tid = threadIdx.x;
  const int w = tid >> 6, lane = tid & 63;
  const int quad = lane >> 4, l15 = lane & 15;
  const int id = blockIdx.x;
  const int b = (id & 7) | (((id >> 3) & 3) << 3);  // batch -> XCD id&7
  const int s0 = (id >> 5) * 16;
  const int myrow = 4 * w + quad;
  const int sglob = s0 + myrow;

  const ushort *qb = Q + ((long)(b << 3) * 512 + s0) * 32 + l15 * 32 + quad * 8;
  const ushort *kb =
      K + (long)(b << 3) * 512 * 32 + (w * 128 + l15) * 32 + quad * 8;
  short8 bq = *(const short8 *)qb;  // head 0 fragments
  short8 ak[8];
#pragma unroll
  for (int jl = 0; jl < 8; ++jl) ak[jl] = *(const short8 *)(kb + jl * 512);

  float avgacc[8][4] = {};
#pragma unroll 1
  for (int h = 0; h < 8; ++h) {
    f32x4 acc[8];
    __builtin_amdgcn_s_setprio(1);
#pragma unroll
    for (int jl = 0; jl < 8; ++jl)
      acc[jl] = __builtin_amdgcn_mfma_f32_16x16x32_bf16(
          ak[jl], bq, (f32x4){0.f, 0.f, 0.f, 0.f}, 0, 0, 0);
    __builtin_amdgcn_s_setprio(0);
    __syncthreads();
#pragma unroll
    for (int jl = 0; jl < 8; ++jl) {
      const int ch = 32 * w + 4 * jl + quad;
      sc[l15 * 128 + (ch ^ (l15 & 7))] = acc[jl];
    }
    __syncthreads();
    f32x4 z[8];
#pragma unroll
    for (int c = 0; c < 8; ++c) {
      const int ch = l15 + 16 * c;
      z[c] = sc[myrow * 128 + (ch ^ (myrow & 7))];
    }
    // prefetch next head's fragments; latency hides under the solve below
    if (h < 7) {
      bq = *(const short8 *)(qb + (h + 1) * 16384);
#pragma unroll
      for (int jl = 0; jl < 8; ++jl)
        ak[jl] = *(const short8 *)(kb + (h + 1) * 16384 + jl * 512);
    }
#pragma unroll
    for (int c = 0; c < 8; ++c)
#pragma unroll
      for (int r = 0; r < 4; ++r)
        if (64 * c + 4 * l15 + r == sglob) z[c][r] = -1e30f;
    // top-3 scan: q0 >= q1 >= q2 of this lane's 32 values
    float q0 = -3e38f, q1 = -3e38f, q2 = -3e38f;
#pragma unroll
    for (int c = 0; c < 8; ++c)
#pragma unroll
      for (int r = 0; r < 4; ++r) {
        const float v = z[c][r];
        const float t1 = fminf(q0, v);
        q0 = fmaxf(q0, v);
        const float t2 = fminf(q1, t1);
        q1 = fmaxf(q1, t1);
        q2 = fmaxf(q2, t2);
      }
    const float M = dpp_max16(q0);
    const float thr = M - 1.0f;
    float tau = thr;
    float cOld = -1.f;
    if (__any(q2 > thr)) {
      // slow path: some lane holds >=3 candidates — full scan (rare)
#pragma unroll 1
      for (int it = 0; it < 32; ++it) {
        float s = 0.f, c = 0.f;
#pragma unroll
        for (int cc = 0; cc < 8; ++cc)
#pragma unroll
          for (int r = 0; r < 4; ++r) {
            const bool p = z[cc][r] > tau;
            s += p ? z[cc][r] : 0.f;
            c += p ? 1.f : 0.f;
          }
        s = dpp_sum16(s);
        c = dpp_sum16(c);
        const bool stable = (c == cOld);
        if (__all(stable)) break;
        if (!stable) {
          tau = (s - 1.f) / c;
          cOld = c;
        }
      }
    } else {
      // fast path: candidates per lane are within {q0,q1}; tau >= thr is
      // monotone so elements <= thr can never enter the support.
#pragma unroll 1
      for (int it = 0; it < 32; ++it) {
        const bool p0 = q0 > tau, p1 = q1 > tau;
        float s = (p0 ? q0 : 0.f) + (p1 ? q1 : 0.f);
        float c = (p0 ? 1.f : 0.f) + (p1 ? 1.f : 0.f);
        s = dpp_sum16(s);
        c = dpp_sum16(c);
        const bool stable = (c == cOld);
        if (__all(stable)) break;
        if (!stable) {
          tau = (s - 1.f) / c;
          cOld = c;
        }
      }
    }
#pragma unroll
    for (int c = 0; c < 8; ++c)
#pragma unroll
      for (int r = 0; r < 4; ++r)
        avgacc[c][r] += fmaxf(z[c][r] - tau, 0.f);
  }
  // avg write (fp32, required output) + bf16 p-tile into reused LDS.
  __syncthreads();  // all waves done reading sc for head 7
  ushort *pl = (ushort *)sc;
  float *dst = avg + ((b * 512 + sglob) << 9) + 4 * l15;
#pragma unroll
  for (int c = 0; c < 8; ++c) {
    float4 o;
    o.x = avgacc[c][0] * 0.125f;
    o.y = avgacc[c][1] * 0.125f;
    o.z = avgacc[c][2] * 0.125f;
    o.w = avgacc[c][3] * 0.125f;
    *(float4 *)(dst + 64 * c) = o;
    ushort4 pv;
    pv.x = f2bf(o.x); pv.y = f2bf(o.y); pv.z = f2bf(o.z); pv.w = f2bf(o.w);
    // row myrow, cols 64c+4*l15..+3; XOR-swizzle bits 4..6 by row (T2)
    *(ushort4 *)((char *)pl +
                 ((myrow * 1024 + 128 * c + 8 * l15) ^ ((myrow & 7) << 4))) = pv;
  }
  __syncthreads();
  // fused out = avg . u : wave w covers e in [64w, 64w+64), all 16 s-rows.
  // uT chunk layout: [b][t>>5][e][t&31] -> each uf wave-load = 1KB contiguous.
  const ushort *ub = U + (long)b * 131072 + (64 * w + l15) * 32 + quad * 8;
  f32x4 oacc[4] = {{0.f, 0.f, 0.f, 0.f},
                   {0.f, 0.f, 0.f, 0.f},
                   {0.f, 0.f, 0.f, 0.f},
                   {0.f, 0.f, 0.f, 0.f}};
#pragma unroll
  for (int ks = 0; ks < 16; ++ks) {
    const short8 pf = *(const short8 *)(
        (char *)pl + (l15 * 1024 + ((ks * 64 + quad * 16) ^ ((l15 & 7) << 4))));
    __builtin_amdgcn_s_setprio(1);
#pragma unroll
    for (int nt = 0; nt < 4; ++nt) {
      const short8 uf = *(const short8 *)(ub + (long)ks * 8192 + nt * 512);
      oacc[nt] = __builtin_amdgcn_mfma_f32_16x16x32_bf16(uf, pf, oacc[nt], 0, 0, 0);
    }
    __builtin_amdgcn_s_setprio(0);
  }
  float *ob = out + ((long)b * 512 + s0 + l15) * 256 + 64 * w + 4 * quad;
#pragma unroll
  for (int nt = 0; nt < 4; ++nt) {
    float4 st;
    st.x = oacc[nt][0]; st.y = oacc[nt][1];
    st.z = oacc[nt][2]; st.w = oacc[nt][3];
    *(float4 *)(ob + 16 * nt) = st;
  }
}

extern "C" void kernel_launch(void* const* d_in, const int* in_sizes, int n_in,
                              void* d_out, int out_size, void* d_ws, size_t ws_size,
                              hipStream_t stream) {
  const float *x  = (const float *)d_in[0];
  const float *Wq = (const float *)d_in[1];
  const float *bq = (const float *)d_in[2];
  const float *Wk = (const float *)d_in[3];
  const float *bk = (const float *)d_in[4];
  const float *Wv = (const float *)d_in[5];
  const float *bv = (const float *)d_in[6];
  const float *Wo = (const float *)d_in[7];
  const float *bo = (const float *)d_in[8];

  float *out = (float *)d_out;                 // [B,S,D]
  float *avg = out + 32 * 512 * 256;           // [B,S,S] fp32

  // ws (ushort units): xbf | qbf | kbf | uT | wq,wk,wvo | bvo  ~= 33.9 MB
  ushort *ws16 = (ushort *)d_ws;
  ushort *xbf = ws16;                          // [16384][256] bf16
  ushort *qbf = ws16 + 4194304;                // [B,H,S,32] bf16 (pre-scaled)
  ushort *kbf = ws16 + 8388608;                // [B,H,S,32] bf16
  ushort *uT  = ws16 + 12582912;               // [B][16 tc][256 e][32 t] bf16
  ushort *wbf = ws16 + 16777216;               // Wq|Wk|Wvo bf16, 65536 each
  float  *bvo = (float *)(ws16 + 16973824);    // [256] fp32

  prep<<<dim3(4480), dim3(256), 0, stream>>>(x, Wq, Wk, Wo, Wv, bv, bo, xbf,
                                             wbf, wbf + 131072, bvo);
  gemm_all<<<dim3(1024), dim3(256), 0, stream>>>(xbf, wbf, wbf + 131072, bq,
                                                 bk, bvo, qbf, kbf, uT);
  attn_sparsemax_fused<<<dim3(1024), dim3(256), 0, stream>>>(qbf, kbf, uT,
                                                             avg, out);
}